// Round 6
// baseline (706.844 us; speedup 1.0000x reference)
//
#include <hip/hip_runtime.h>
#include <hip/hip_bf16.h>

#define BB   2
#define SS   2048
#define HH   2048
#define NHH  16
#define QLL  1536
#define KVLL 512
#define NOPE_D 128
#define ROPE_D 64
#define QKH_D  192
#define VD_D   128
#define MROWS  (BB*SS)           // 4096 token rows

typedef __attribute__((ext_vector_type(8))) short bf16x8;   // 8 bf16 (4 VGPRs)
typedef __attribute__((ext_vector_type(4))) float f32x4;    // MFMA accumulator

__device__ inline float bf2f(unsigned short u) {
    union { float f; unsigned int i; } v; v.i = ((unsigned int)u) << 16; return v.f;
}
__device__ inline unsigned short f2bf(float f) {
    union { float f; unsigned int u; } v; v.f = f;
    unsigned int r = v.u + 0x7fffu + ((v.u >> 16) & 1u);
    return (unsigned short)(r >> 16);
}

// async global->LDS, 16 B per lane.  LDS placement is wave-uniform base +
// lane*16; callers pass l = base + lane_linear_slot*8 (ushorts) to match.
__device__ __forceinline__ void gload_lds16(const ushort* g, ushort* l)
{
    __builtin_amdgcn_global_load_lds(
        (const __attribute__((address_space(1))) void*)(g),
        (__attribute__((address_space(3))) void*)(l), 16, 0, 0);
}

// ---------------------------------------------------------------------------
// f32 -> bf16 convert (grid-stride over 4-element groups)
// ---------------------------------------------------------------------------
__global__ void conv_bf(const float* __restrict__ in, ushort* __restrict__ out, int n4)
{
    int i = blockIdx.x * 256 + threadIdx.x;
    int stride = gridDim.x * 256;
    for (; i < n4; i += stride) {
        float4 v = ((const float4*)in)[i];
        ushort4 u;
        u.x = f2bf(v.x); u.y = f2bf(v.y); u.z = f2bf(v.z); u.w = f2bf(v.w);
        ((ushort4*)out)[i] = u;
    }
}

// ---------------------------------------------------------------------------
// All-bf16 MFMA NT GEMM: C[m,n] = sum_k A[m,k]*B[n,k] (+bias[n]).
// 128x128 tile, BK=64, 256 threads (4 waves, each 64x64 via 4x4 frags of
// 16x16x32).  Staging via global_load_lds (16B/lane), LDS layout
// [kchunk 0..7][row 0..127] x 16B -> frag reads are 2-way (free).
// M mult of 128; N guarded (stage rows clamped, stores skipped); K mult of 64.
// z-batching: ptr += (z>>4)*Xb + (z&15)*Xh.
// ---------------------------------------------------------------------------
template<typename TC>
__launch_bounds__(256, 2)
__global__ void gemm_bf(const ushort* __restrict__ A, int lda, size_t Ab, size_t Ah,
                        const ushort* __restrict__ B, int ldb, size_t Bb, size_t Bh,
                        const float* __restrict__ bias,
                        TC* __restrict__ C, int ldc, size_t Cb, size_t Ch,
                        int M, int N, int K)
{
    __shared__ ushort As[128 * 64];
    __shared__ ushort Bs[128 * 64];
    const int z = blockIdx.z, bz = z >> 4, hz = z & 15;
    A += (size_t)bz * Ab + (size_t)hz * Ah;
    B += (size_t)bz * Bb + (size_t)hz * Bh;
    C += (size_t)bz * Cb + (size_t)hz * Ch;
    const int m0 = blockIdx.y * 128, n0 = blockIdx.x * 128;
    const int tid = threadIdx.x, w = tid >> 6, lane = tid & 63;
    const int l15 = lane & 15, q = lane >> 4;

    f32x4 acc[4][4];
#pragma unroll
    for (int i = 0; i < 4; i++)
#pragma unroll
        for (int j = 0; j < 4; j++) acc[i][j] = (f32x4){0.f, 0.f, 0.f, 0.f};

    const int mrow = 64 * (w & 1) + l15;   // + 16*mt
    const int nrow = 64 * (w >> 1) + l15;  // + 16*nt

    for (int k0 = 0; k0 < K; k0 += 64) {
        // stage: 16 slots of (kchunk c, row-half rh); wave w takes slots 4w..4w+3
#pragma unroll
        for (int i = 0; i < 4; i++) {
            int S = 4 * w + i;
            int c = S >> 1, rh = S & 1;
            int row = rh * 64 + lane;
            gload_lds16(A + (size_t)(m0 + row) * lda + k0 + c * 8,
                        As + (c * 128 + row) * 8);
            int rb = n0 + row; if (rb > N - 1) rb = N - 1;
            gload_lds16(B + (size_t)rb * ldb + k0 + c * 8,
                        Bs + (c * 128 + row) * 8);
        }
        __syncthreads();
#pragma unroll
        for (int ks = 0; ks < 2; ks++) {
            bf16x8 af[4], bf[4];
#pragma unroll
            for (int mt = 0; mt < 4; mt++)
                af[mt] = *(const bf16x8*)(As + ((ks * 4 + q) * 128 + mrow + 16 * mt) * 8);
#pragma unroll
            for (int nt = 0; nt < 4; nt++)
                bf[nt] = *(const bf16x8*)(Bs + ((ks * 4 + q) * 128 + nrow + 16 * nt) * 8);
#pragma unroll
            for (int mt = 0; mt < 4; mt++)
#pragma unroll
                for (int nt = 0; nt < 4; nt++)
                    acc[mt][nt] = __builtin_amdgcn_mfma_f32_16x16x32_bf16(af[mt], bf[nt], acc[mt][nt], 0, 0, 0);
        }
        __syncthreads();
    }

#pragma unroll
    for (int nt = 0; nt < 4; nt++) {
        int n = n0 + nrow + 16 * nt;
        if (n >= N) continue;
        float bv = bias ? bias[n] : 0.f;
#pragma unroll
        for (int mt = 0; mt < 4; mt++) {
#pragma unroll
            for (int r = 0; r < 4; r++) {
                int m = m0 + 64 * (w & 1) + 16 * mt + 4 * q + r;
                float v = acc[mt][nt][r] + bv;
                if constexpr (sizeof(TC) == 2) C[(size_t)m * ldc + n] = f2bf(v);
                else                           C[(size_t)m * ldc + n] = v;
            }
        }
    }
}

// ---------------------------------------------------------------------------
// RMSNorm f32 in -> bf16 out.  One 256-thread block per row.
// ---------------------------------------------------------------------------
__launch_bounds__(256)
__global__ void rmsnorm_bf(const float* __restrict__ x, const float* __restrict__ w,
                           ushort* __restrict__ o, int width)
{
    const float* xr = x + (size_t)blockIdx.x * width;
    ushort* orow = o + (size_t)blockIdx.x * width;
    float ss = 0.f;
    for (int i = threadIdx.x; i < width; i += 256) { float v = xr[i]; ss += v * v; }
    __shared__ float red[256];
    red[threadIdx.x] = ss; __syncthreads();
    for (int off = 128; off > 0; off >>= 1) {
        if (threadIdx.x < off) red[threadIdx.x] += red[threadIdx.x + off];
        __syncthreads();
    }
    float r = rsqrtf(red[0] / (float)width + 1e-6f);
    for (int i = threadIdx.x; i < width; i += 256)
        orow[i] = f2bf(w[i] * xr[i] * r);
}

__device__ inline float rope_val(float xj, float xo, int j, int s)
{
    int i = j & 31;
    float freq = powf(10000.f, -(float)i / 32.f);
    float a = (float)s * freq;
    float sn, cs; sincosf(a, &sn, &cs);
    float other = (j < 32) ? -xo : xo;
    return xj * cs + other * sn;
}

// kv finalize: rms_norm latent 512 + rope pe 64 -> kvbf (4096x576 bf16)
__launch_bounds__(256)
__global__ void finalize_kv(const float* __restrict__ kvf, const float* __restrict__ w,
                            ushort* __restrict__ kvbf)
{
    int m = blockIdx.x, s = m & (SS - 1);
    const float* xr = kvf + (size_t)m * 576;
    float ss = 0.f;
    for (int i = threadIdx.x; i < 512; i += 256) { float v = xr[i]; ss += v * v; }
    __shared__ float red[256];
    red[threadIdx.x] = ss; __syncthreads();
    for (int off = 128; off > 0; off >>= 1) {
        if (threadIdx.x < off) red[threadIdx.x] += red[threadIdx.x + off];
        __syncthreads();
    }
    float r = rsqrtf(red[0] / 512.f + 1e-6f);
    for (int i = threadIdx.x; i < 512; i += 256)
        kvbf[(size_t)m * 576 + i] = f2bf(w[i] * xr[i] * r);
    if (threadIdx.x < 64) {
        int j = threadIdx.x;
        float xj = xr[512 + j], xo = xr[512 + (j ^ 32)];
        kvbf[(size_t)m * 576 + 512 + j] = f2bf(rope_val(xj, xo, j, s));
    }
}

// RoPE q_pe in place on qbuf bf16.  grid (4096,4) x 256; wave owns one head.
__global__ void rope_q_kernel(ushort* __restrict__ qbuf)
{
    int m = blockIdx.x, s = m & (SS - 1);
    int w = threadIdx.x >> 6, j = threadIdx.x & 63;
    int h = blockIdx.y * 4 + w;
    ushort* p = qbuf + (size_t)m * 3072 + h * QKH_D + NOPE_D;
    float xj = bf2f(p[j]);
    float xo = bf2f(p[j ^ 32]);
    p[j] = f2bf(rope_val(xj, xo, j, s));
}

// copy k_pe cols into Kf[...][128..191] for all heads.  grid 4096 x 256.
__global__ void copy_kpe(const ushort* __restrict__ kvbf, ushort* __restrict__ Kf)
{
    int m = blockIdx.x, b = m >> 11, t = m & (SS - 1);
    int j = threadIdx.x & 63;
    ushort v = kvbf[(size_t)m * 576 + 512 + j];
    for (int h = threadIdx.x >> 6; h < NHH; h += 4)
        Kf[((size_t)(b * NHH + h) * SS + t) * QKH_D + NOPE_D + j] = v;
}

// ---------------------------------------------------------------------------
// MFMA flash attention, materialized per-head K/V.  One 64-q-row tile per
// block, 1024 blocks, launched big-tiles-first (LPT packing).  64-t steps.
// Wave w: scores for m-tile rows [s0+16w,+16); PV d-slice [32w,+32) as
// O^T = VT-frags (global) @ P-frags (LDS).
// K-tile staged via global_load_lds into [chunk 0..23][row 0..63] x 16B.
// ---------------------------------------------------------------------------
#define SCL  0.10411760f  // (1/sqrt(192)) * log2(e)
#define PTL  72           // Pt row length (64+8 pad)

__launch_bounds__(256, 4)
__global__ void attn_mfma(const ushort* __restrict__ qbuf, const ushort* __restrict__ Kf,
                          const ushort* __restrict__ VT, const int* __restrict__ mask,
                          ushort* __restrict__ o_heads)
{
    __shared__ ushort Kt[24 * 64 * 8];  // 24,576 B
    __shared__ ushort Pt[64 * PTL];     //  9,216 B
    __shared__ float alpha_sh[64];
    __shared__ float linv_sh[64];

    const int tid = threadIdx.x, w = tid >> 6, lane = tid & 63;
    const int l15 = lane & 15, q = lane >> 4;

    const int tile = 31 - (blockIdx.x >> 5);   // big tiles dispatch first
    const int bh = blockIdx.x & 31;
    const int b = bh >> 4, h = bh & 15;
    const int s0 = tile * 64;

    const ushort* Kf_bh = Kf + (size_t)bh * SS * QKH_D;
    const ushort* VT_bh = VT + (size_t)bh * VD_D * SS;
    const int* mrow = mask + b * SS;

    // Q A-frags: rows s0+16w..+15, 6 k-chunks of 32 over the 192 dims
    bf16x8 qf[6];
    {
        const ushort* qbase = qbuf + ((size_t)(b * SS) + s0 + 16 * w + l15) * 3072 + h * QKH_D + q * 8;
#pragma unroll
        for (int k = 0; k < 6; k++) qf[k] = *(const bf16x8*)(qbase + k * 32);
    }

    f32x4 Oacc[2][4];
#pragma unroll
    for (int mt = 0; mt < 2; mt++)
#pragma unroll
        for (int nt = 0; nt < 4; nt++) Oacc[mt][nt] = (f32x4){0.f, 0.f, 0.f, 0.f};
    float m_i[4] = {-3e38f, -3e38f, -3e38f, -3e38f};
    float l_i[4] = {0.f, 0.f, 0.f, 0.f};

    const int nsteps = tile + 1;
    for (int st = 0; st < nsteps; st++) {
        const int t0 = st * 64;
        // ---- stage K-tile (64 rows x 24 chunks), wave w: chunks 6w..6w+5 ----
#pragma unroll
        for (int i = 0; i < 6; i++) {
            int c = 6 * w + i;
            gload_lds16(Kf_bh + (size_t)(t0 + lane) * QKH_D + c * 8,
                        Kt + (c * 64 + lane) * 8);
        }
        __syncthreads();
        // ---- scores S(16 x 64) for my m-tile ----
        f32x4 sa[4];
#pragma unroll
        for (int c = 0; c < 4; c++) sa[c] = (f32x4){0.f, 0.f, 0.f, 0.f};
#pragma unroll
        for (int k = 0; k < 6; k++) {
#pragma unroll
            for (int c = 0; c < 4; c++) {
                bf16x8 kb = *(const bf16x8*)(Kt + ((4 * k + q) * 64 + 16 * c + l15) * 8);
                sa[c] = __builtin_amdgcn_mfma_f32_16x16x32_bf16(qf[k], kb, sa[c], 0, 0, 0);
            }
        }
        // ---- online softmax over 64 cols ----
        int mv[4];
#pragma unroll
        for (int c = 0; c < 4; c++) mv[c] = mrow[t0 + 16 * c + l15];
        float alpha[4];
#pragma unroll
        for (int r = 0; r < 4; r++) {
            const int srow = s0 + 16 * w + 4 * q + r;
            float s_c[4];
#pragma unroll
            for (int c = 0; c < 4; c++) {
                s_c[c] = sa[c][r] * SCL;
                int col = t0 + 16 * c + l15;
                if (col > srow || mv[c] == 0) s_c[c] = -1e30f;
            }
            float mx = fmaxf(fmaxf(s_c[0], s_c[1]), fmaxf(s_c[2], s_c[3]));
            mx = fmaxf(mx, __shfl_xor(mx, 1)); mx = fmaxf(mx, __shfl_xor(mx, 2));
            mx = fmaxf(mx, __shfl_xor(mx, 4)); mx = fmaxf(mx, __shfl_xor(mx, 8));
            float mn = fmaxf(m_i[r], mx);
            alpha[r] = exp2f(m_i[r] - mn);
            m_i[r] = mn;
            float ps = 0.f;
            const int prow = 16 * w + 4 * q + r;
#pragma unroll
            for (int c = 0; c < 4; c++) {
                float pc = (s_c[c] <= -1e29f) ? 0.f : exp2f(s_c[c] - mn);
                ps += pc;
                Pt[prow * PTL + 16 * c + l15] = f2bf(pc);
            }
            ps += __shfl_xor(ps, 1); ps += __shfl_xor(ps, 2);
            ps += __shfl_xor(ps, 4); ps += __shfl_xor(ps, 8);
            l_i[r] = l_i[r] * alpha[r] + ps;
        }
        if (l15 == 0) {
#pragma unroll
            for (int r = 0; r < 4; r++) alpha_sh[16 * w + 4 * q + r] = alpha[r];
        }
        __syncthreads();
        // ---- PV: O^T d-slice [32w,+32) over 64 s, 64 t ----
        float av[4];
#pragma unroll
        for (int nt = 0; nt < 4; nt++) av[nt] = alpha_sh[16 * nt + l15];
#pragma unroll
        for (int mt = 0; mt < 2; mt++)
#pragma unroll
            for (int nt = 0; nt < 4; nt++) {
                Oacc[mt][nt][0] *= av[nt]; Oacc[mt][nt][1] *= av[nt];
                Oacc[mt][nt][2] *= av[nt]; Oacc[mt][nt][3] *= av[nt];
            }
        bf16x8 pb[4][2];
#pragma unroll
        for (int nt = 0; nt < 4; nt++)
#pragma unroll
            for (int kt = 0; kt < 2; kt++)
                pb[nt][kt] = *(const bf16x8*)(Pt + (16 * nt + l15) * PTL + kt * 32 + q * 8);
#pragma unroll
        for (int mt = 0; mt < 2; mt++) {
#pragma unroll
            for (int kt = 0; kt < 2; kt++) {
                bf16x8 af = *(const bf16x8*)(VT_bh + (size_t)(32 * w + 16 * mt + l15) * SS + t0 + kt * 32 + q * 8);
#pragma unroll
                for (int nt = 0; nt < 4; nt++)
                    Oacc[mt][nt] = __builtin_amdgcn_mfma_f32_16x16x32_bf16(af, pb[nt][kt], Oacc[mt][nt], 0, 0, 0);
            }
        }
        __syncthreads();
    }

    // ---- epilogue: 1/l then write o_heads ----
    if (l15 == 0) {
#pragma unroll
        for (int r = 0; r < 4; r++)
            linv_sh[16 * w + 4 * q + r] = (l_i[r] > 0.f) ? 1.f / l_i[r] : 0.f;
    }
    __syncthreads();
#pragma unroll
    for (int mt = 0; mt < 2; mt++)
#pragma unroll
        for (int nt = 0; nt < 4; nt++) {
            float lv = linv_sh[16 * nt + l15];
            int s = s0 + 16 * nt + l15;
            int d = 32 * w + 16 * mt + 4 * q;
            ushort4 pk;
            pk.x = f2bf(Oacc[mt][nt][0] * lv); pk.y = f2bf(Oacc[mt][nt][1] * lv);
            pk.z = f2bf(Oacc[mt][nt][2] * lv); pk.w = f2bf(Oacc[mt][nt][3] * lv);
            *(ushort4*)(o_heads + (size_t)(b * SS + s) * 2048 + h * VD_D + d) = pk;
        }
}

extern "C" void kernel_launch(void* const* d_in, const int* in_sizes, int n_in,
                              void* d_out, int out_size, void* d_ws, size_t ws_size,
                              hipStream_t stream)
{
    const float* x        = (const float*)d_in[0];
    const int*   mask     = (const int*)d_in[1];
    const float* wq_a_w   = (const float*)d_in[2];
    const float* wq_a_b   = (const float*)d_in[3];
    const float* q_norm_w = (const float*)d_in[4];
    const float* wq_b_w   = (const float*)d_in[5];
    const float* wq_b_b   = (const float*)d_in[6];
    const float* wkv_a_w  = (const float*)d_in[7];
    const float* wkv_a_b  = (const float*)d_in[8];
    const float* kv_norm_w= (const float*)d_in[9];
    const float* wkv_b_w  = (const float*)d_in[10];
    const float* wo_w     = (const float*)d_in[11];
    const float* wo_b     = (const float*)d_in[12];
    float* out = (float*)d_out;

    // Workspace layout (108,527,616 B; <= proven available):
    //  A [0,25165824):          wq_a_bf (ph0-1) -> qbuf bf16 (ph3-10)
    //  B [25165824,50331648):   q_a f32 (ph1-2) -> Kf bf16 (ph7-10)
    //  C [50331648,67108864):   x_bf (ph0-4)    -> VT bf16 (ph9-10)
    //  D [67108864,83886080):   q_a_bf (ph2-3) / kvf f32 (ph4-5) / o_heads (ph10-11)
    //  E [83886080,93323264):   wq_b_bf (ph0-3) -> kvbf (ph5-10)
    //  F [93323264,97517568):   wkv_b_bf (ph0-9)
    //  G [97517568,105906176):  wo_bf (ph0-11)
    //  H [105906176,108527616): wkv_a_bf padded to 640 rows (ph0-4)
    char* W = (char*)d_ws;
    ushort* wq_a_bf = (ushort*)(W + 0);
    ushort* qbuf    = (ushort*)(W + 0);
    float*  q_a     = (float*)(W + 25165824);
    ushort* Kf      = (ushort*)(W + 25165824);
    ushort* x_bf    = (ushort*)(W + 50331648);
    ushort* VT      = (ushort*)(W + 50331648);
    ushort* q_a_bf  = (ushort*)(W + 67108864);
    float*  kvf     = (float*)(W + 67108864);
    ushort* o_heads = (ushort*)(W + 67108864);
    ushort* wq_b_bf = (ushort*)(W + 83886080);
    ushort* kvbf    = (ushort*)(W + 83886080);
    ushort* wkv_b_bf= (ushort*)(W + 93323264);
    ushort* wo_bf   = (ushort*)(W + 97517568);
    ushort* wkv_a_bf= (ushort*)(W + 105906176);

    // 0. converts to bf16
    conv_bf<<<2048, 256, 0, stream>>>(x, x_bf, MROWS * HH / 4);
    conv_bf<<<2048, 256, 0, stream>>>(wq_a_w, wq_a_bf, QLL * HH / 4);
    conv_bf<<<2048, 256, 0, stream>>>(wq_b_w, wq_b_bf, 3072 * QLL / 4);
    conv_bf<<<1024, 256, 0, stream>>>(wkv_a_w, wkv_a_bf, 576 * HH / 4);
    conv_bf<<<1024, 256, 0, stream>>>(wkv_b_w, wkv_b_bf, NHH * 256 * 512 / 4);
    conv_bf<<<2048, 256, 0, stream>>>(wo_w, wo_bf, HH * 2048 / 4);

    // 1. q_a = x @ wq_a^T + b        (f32 C)
    gemm_bf<float><<<dim3(QLL/128, MROWS/128, 1), 256, 0, stream>>>(
        x_bf, HH, 0, 0, wq_a_bf, HH, 0, 0, wq_a_b, q_a, QLL, 0, 0, MROWS, QLL, HH);
    // 2. rms_norm -> q_a_bf
    rmsnorm_bf<<<MROWS, 256, 0, stream>>>(q_a, q_norm_w, q_a_bf, QLL);
    // 3. q = q_a_bf @ wq_b^T + b -> qbuf bf16
    gemm_bf<ushort><<<dim3(3072/128, MROWS/128, 1), 256, 0, stream>>>(
        q_a_bf, QLL, 0, 0, wq_b_bf, QLL, 0, 0, wq_b_b, qbuf, 3072, 0, 0, MROWS, 3072, QLL);
    // 4. kv_full = x @ wkv_a^T + b   (f32 C, N=576 guarded; weight padded to 640 rows)
    gemm_bf<float><<<dim3(5, MROWS/128, 1), 256, 0, stream>>>(
        x_bf, HH, 0, 0, wkv_a_bf, HH, 0, 0, wkv_a_b, kvf, 576, 0, 0, MROWS, 576, HH);
    // 5. finalize kv (rms + rope) -> kvbf
    finalize_kv<<<MROWS, 256, 0, stream>>>(kvf, kv_norm_w, kvbf);
    // 6. rope q_pe in place on qbuf
    rope_q_kernel<<<dim3(MROWS, 4), 256, 0, stream>>>(qbuf);
    // 7. Kf[b,h] = kv_lat @ W_UK[h]^T   (M=2048,N=128,K=512, z=32)
    gemm_bf<ushort><<<dim3(1, SS/128, 32), 256, 0, stream>>>(
        kvbf, 576, (size_t)SS * 576, 0,
        wkv_b_bf, 512, 0, (size_t)256 * 512,
        nullptr, Kf, QKH_D, (size_t)NHH * SS * QKH_D, (size_t)SS * QKH_D,
        SS, NOPE_D, 512);
    // 8. k_pe broadcast into Kf cols 128..191
    copy_kpe<<<MROWS, 256, 0, stream>>>(kvbf, Kf);
    // 9. VT[b,h] = W_UV[h] @ kv_lat^T   (M=128,N=2048,K=512, z=32)
    gemm_bf<ushort><<<dim3(SS/128, 1, 32), 256, 0, stream>>>(
        wkv_b_bf + (size_t)128 * 512, 512, 0, (size_t)256 * 512,
        kvbf, 576, (size_t)SS * 576, 0,
        nullptr, VT, SS, (size_t)NHH * VD_D * SS, (size_t)VD_D * SS,
        VD_D, SS, 512);
    // 10. MFMA flash attention -> o_heads bf16 (1024 blocks, LPT order)
    attn_mfma<<<BB * NHH * 32, 256, 0, stream>>>(qbuf, Kf, VT, mask, o_heads);
    // 11. out = o_heads @ wo^T + b
    gemm_bf<float><<<dim3(HH/128, MROWS/128, 1), 256, 0, stream>>>(
        o_heads, NHH * VD_D, 0, 0, wo_bf, NHH * VD_D, 0, 0, wo_b, out, HH, 0, 0,
        MROWS, HH, NHH * VD_D);
}

// Round 7
// 545.831 us; speedup vs baseline: 1.2950x; 1.2950x over previous
//
#include <hip/hip_runtime.h>
#include <hip/hip_bf16.h>

#define BB   2
#define SS   2048
#define HH   2048
#define NHH  16
#define QLL  1536
#define KVLL 512
#define NOPE_D 128
#define ROPE_D 64
#define QKH_D  192
#define VD_D   128
#define MROWS  (BB*SS)           // 4096 token rows

typedef __attribute__((ext_vector_type(8))) short bf16x8;   // 8 bf16 (4 VGPRs)
typedef __attribute__((ext_vector_type(4))) float f32x4;    // MFMA accumulator

__device__ inline float bf2f(unsigned short u) {
    union { float f; unsigned int i; } v; v.i = ((unsigned int)u) << 16; return v.f;
}
__device__ inline unsigned short f2bf(float f) {
    union { float f; unsigned int u; } v; v.f = f;
    unsigned int r = v.u + 0x7fffu + ((v.u >> 16) & 1u);
    return (unsigned short)(r >> 16);
}

// async global->LDS, 16 B per lane.  LDS dest = wave-uniform base + lane*16.
__device__ __forceinline__ void gload_lds16(const ushort* g, ushort* l)
{
    __builtin_amdgcn_global_load_lds(
        (const __attribute__((address_space(1))) void*)(g),
        (__attribute__((address_space(3))) void*)(l), 16, 0, 0);
}

// ---------------------------------------------------------------------------
// f32 -> bf16 convert (grid-stride over 4-element groups)
// ---------------------------------------------------------------------------
__global__ void conv_bf(const float* __restrict__ in, ushort* __restrict__ out, int n4)
{
    int i = blockIdx.x * 256 + threadIdx.x;
    int stride = gridDim.x * 256;
    for (; i < n4; i += stride) {
        float4 v = ((const float4*)in)[i];
        ushort4 u;
        u.x = f2bf(v.x); u.y = f2bf(v.y); u.z = f2bf(v.z); u.w = f2bf(v.w);
        ((ushort4*)out)[i] = u;
    }
}

// ---------------------------------------------------------------------------
// All-bf16 MFMA NT GEMM: C[m,n] = sum_k A[m,k]*B[n,k] (+bias[n]).
// 128x128 tile, BK=64, 256 threads (4 waves, each 64x64 via 4x4 frags of
// 16x16x32).  Staging: global_load_lds 16B/lane, lane=(row8*8+chunk),
// global chunk XOR'd with row&7 -> coalesced 128B segments AND conflict-free
// LDS frag reads (2-way).  LDS[row][c'] holds global chunk c'^(row&7).
// M mult of 128; N guarded; K mult of 64.  z: ptr += (z>>4)*Xb + (z&15)*Xh.
// ---------------------------------------------------------------------------
template<typename TC>
__launch_bounds__(256, 3)
__global__ void gemm_bf(const ushort* __restrict__ A, int lda, size_t Ab, size_t Ah,
                        const ushort* __restrict__ B, int ldb, size_t Bb, size_t Bh,
                        const float* __restrict__ bias,
                        TC* __restrict__ C, int ldc, size_t Cb, size_t Ch,
                        int M, int N, int K)
{
    __shared__ ushort As[128 * 64];
    __shared__ ushort Bs[128 * 64];
    const int z = blockIdx.z, bz = z >> 4, hz = z & 15;
    A += (size_t)bz * Ab + (size_t)hz * Ah;
    B += (size_t)bz * Bb + (size_t)hz * Bh;
    C += (size_t)bz * Cb + (size_t)hz * Ch;
    const int m0 = blockIdx.y * 128, n0 = blockIdx.x * 128;
    const int tid = threadIdx.x, w = tid >> 6, lane = tid & 63;
    const int l15 = lane & 15, q = lane >> 4;
    const int r7 = lane >> 3, c7 = lane & 7;   // staging row-in-group / chunk
    const int xork = l15 & 7;                  // frag-read XOR key

    f32x4 acc[4][4];
#pragma unroll
    for (int i = 0; i < 4; i++)
#pragma unroll
        for (int j = 0; j < 4; j++) acc[i][j] = (f32x4){0.f, 0.f, 0.f, 0.f};

    const int mrow = 64 * (w & 1) + l15;   // + 16*mt
    const int nrow = 64 * (w >> 1) + l15;  // + 16*nt

    for (int k0 = 0; k0 < K; k0 += 64) {
#pragma unroll
        for (int i = 0; i < 4; i++) {
            int g = 4 * w + i;             // 16 row-groups of 8 rows
            int row = g * 8 + r7;
            int ch = c7 ^ r7;              // permuted chunk within the row
            gload_lds16(A + (size_t)(m0 + row) * lda + k0 + ch * 8,
                        As + g * 512 + lane * 8);
            int rb = n0 + row; if (rb > N - 1) rb = N - 1;
            gload_lds16(B + (size_t)rb * ldb + k0 + ch * 8,
                        Bs + g * 512 + lane * 8);
        }
        __syncthreads();
#pragma unroll
        for (int ks = 0; ks < 2; ks++) {
            bf16x8 af[4], bf[4];
            const int ch = ks * 4 + q, chx = ch ^ xork;
#pragma unroll
            for (int mt = 0; mt < 4; mt++)
                af[mt] = *(const bf16x8*)(As + (mrow + 16 * mt) * 64 + chx * 8);
#pragma unroll
            for (int nt = 0; nt < 4; nt++)
                bf[nt] = *(const bf16x8*)(Bs + (nrow + 16 * nt) * 64 + chx * 8);
#pragma unroll
            for (int mt = 0; mt < 4; mt++)
#pragma unroll
                for (int nt = 0; nt < 4; nt++)
                    acc[mt][nt] = __builtin_amdgcn_mfma_f32_16x16x32_bf16(af[mt], bf[nt], acc[mt][nt], 0, 0, 0);
        }
        __syncthreads();
    }

#pragma unroll
    for (int nt = 0; nt < 4; nt++) {
        int n = n0 + nrow + 16 * nt;
        if (n >= N) continue;
        float bv = bias ? bias[n] : 0.f;
#pragma unroll
        for (int mt = 0; mt < 4; mt++) {
#pragma unroll
            for (int r = 0; r < 4; r++) {
                int m = m0 + 64 * (w & 1) + 16 * mt + 4 * q + r;
                float v = acc[mt][nt][r] + bv;
                if constexpr (sizeof(TC) == 2) C[(size_t)m * ldc + n] = f2bf(v);
                else                           C[(size_t)m * ldc + n] = v;
            }
        }
    }
}

// ---------------------------------------------------------------------------
// RMSNorm f32 in -> bf16 out.  One 256-thread block per row.
// ---------------------------------------------------------------------------
__launch_bounds__(256)
__global__ void rmsnorm_bf(const float* __restrict__ x, const float* __restrict__ w,
                           ushort* __restrict__ o, int width)
{
    const float* xr = x + (size_t)blockIdx.x * width;
    ushort* orow = o + (size_t)blockIdx.x * width;
    float ss = 0.f;
    for (int i = threadIdx.x; i < width; i += 256) { float v = xr[i]; ss += v * v; }
    __shared__ float red[256];
    red[threadIdx.x] = ss; __syncthreads();
    for (int off = 128; off > 0; off >>= 1) {
        if (threadIdx.x < off) red[threadIdx.x] += red[threadIdx.x + off];
        __syncthreads();
    }
    float r = rsqrtf(red[0] / (float)width + 1e-6f);
    for (int i = threadIdx.x; i < width; i += 256)
        orow[i] = f2bf(w[i] * xr[i] * r);
}

__device__ inline float rope_val(float xj, float xo, int j, int s)
{
    int i = j & 31;
    float freq = powf(10000.f, -(float)i / 32.f);
    float a = (float)s * freq;
    float sn, cs; sincosf(a, &sn, &cs);
    float other = (j < 32) ? -xo : xo;
    return xj * cs + other * sn;
}

// kv finalize: rms_norm latent 512 + rope pe 64 -> kvbf (4096x576 bf16)
__launch_bounds__(256)
__global__ void finalize_kv(const float* __restrict__ kvf, const float* __restrict__ w,
                            ushort* __restrict__ kvbf)
{
    int m = blockIdx.x, s = m & (SS - 1);
    const float* xr = kvf + (size_t)m * 576;
    float ss = 0.f;
    for (int i = threadIdx.x; i < 512; i += 256) { float v = xr[i]; ss += v * v; }
    __shared__ float red[256];
    red[threadIdx.x] = ss; __syncthreads();
    for (int off = 128; off > 0; off >>= 1) {
        if (threadIdx.x < off) red[threadIdx.x] += red[threadIdx.x + off];
        __syncthreads();
    }
    float r = rsqrtf(red[0] / 512.f + 1e-6f);
    for (int i = threadIdx.x; i < 512; i += 256)
        kvbf[(size_t)m * 576 + i] = f2bf(w[i] * xr[i] * r);
    if (threadIdx.x < 64) {
        int j = threadIdx.x;
        float xj = xr[512 + j], xo = xr[512 + (j ^ 32)];
        kvbf[(size_t)m * 576 + 512 + j] = f2bf(rope_val(xj, xo, j, s));
    }
}

// RoPE q_pe in place on qbuf bf16.  grid (4096,4) x 256; wave owns one head.
__global__ void rope_q_kernel(ushort* __restrict__ qbuf)
{
    int m = blockIdx.x, s = m & (SS - 1);
    int w = threadIdx.x >> 6, j = threadIdx.x & 63;
    int h = blockIdx.y * 4 + w;
    ushort* p = qbuf + (size_t)m * 3072 + h * QKH_D + NOPE_D;
    float xj = bf2f(p[j]);
    float xo = bf2f(p[j ^ 32]);
    p[j] = f2bf(rope_val(xj, xo, j, s));
}

// copy k_pe cols into Kf[...][128..191] for all heads.  grid 4096 x 256.
__global__ void copy_kpe(const ushort* __restrict__ kvbf, ushort* __restrict__ Kf)
{
    int m = blockIdx.x, b = m >> 11, t = m & (SS - 1);
    int j = threadIdx.x & 63;
    ushort v = kvbf[(size_t)m * 576 + 512 + j];
    for (int h = threadIdx.x >> 6; h < NHH; h += 4)
        Kf[((size_t)(b * NHH + h) * SS + t) * QKH_D + NOPE_D + j] = v;
}

// ---------------------------------------------------------------------------
// MFMA flash attention with split-K over t for big tiles.
// Job table (per bh, 45 jobs, sorted big-first): qt<19 -> single block does
// all steps; qt>=19 -> span0 = steps [0,16), span1 = [16, qt+1).  Partial
// spans write (O/l bf16, m/l f32) to scratch; attn_merge combines.
// Block = 4 waves; wave w: score m-tile rows [s0+16w,+16); PV d-slice
// [32w,+32) as O^T.  K-tile staged via coalesced swizzled global_load_lds.
// ---------------------------------------------------------------------------
#define SCL  0.10411760f  // (1/sqrt(192)) * log2(e)
#define PTL  72           // Pt row length (64+8 pad)
#define NJOB 45

__constant__ unsigned char JQT[NJOB] = {18,17,16,19,20,21,22,23,24,25,26,27,28,29,30,31,15,31,14,30,13,29,12,28,11,27,10,26,9,25,8,24,7,23,6,22,5,21,4,20,3,19,2,1,0};
__constant__ unsigned char JT0[NJOB] = { 0, 0, 0, 0, 0, 0, 0, 0, 0, 0, 0, 0, 0, 0, 0, 0, 0,16, 0,16, 0,16, 0,16, 0,16, 0,16, 0,16, 0,16, 0,16, 0,16, 0,16, 0,16, 0,16, 0, 0, 0};
__constant__ unsigned char JT1[NJOB] = {19,18,17,16,16,16,16,16,16,16,16,16,16,16,16,16,16,32,15,31,14,30,13,29,12,28,11,27,10,26, 9,25, 8,24, 7,23, 6,22, 5,21, 4,20, 3, 2, 1};

// LDS index of (row, ch) in the swizzled K-tile (24 chunk-groups of 512 ushorts)
__device__ __forceinline__ int ktidx(int row, int ch) {
    return (((ch >> 3) << 3) + (row >> 3)) * 512 + (row & 7) * 64 + (((ch & 7) ^ (row & 7)) << 3);
}

__launch_bounds__(256, 4)
__global__ void attn_mfma(const ushort* __restrict__ qbuf, const ushort* __restrict__ Kf,
                          const ushort* __restrict__ VT, const int* __restrict__ mask,
                          ushort* __restrict__ o_heads,
                          ushort* __restrict__ Opart, float2* __restrict__ mlbuf)
{
    __shared__ ushort Kt[24 * 512];     // 24,576 B
    __shared__ ushort Pt[64 * PTL];     //  9,216 B
    __shared__ float alpha_sh[64];
    __shared__ float linv_sh[64];

    const int tid = threadIdx.x, w = tid >> 6, lane = tid & 63;
    const int l15 = lane & 15, q = lane >> 4;
    const int r7 = lane >> 3, c7 = lane & 7;

    const int job = blockIdx.x >> 5, bh = blockIdx.x & 31;
    const int b = bh >> 4, h = bh & 15;
    const int qt = JQT[job], t0s = JT0[job], t1s = JT1[job];
    const int s0 = qt * 64;
    const bool partial = (t0s != 0) | (t1s != qt + 1);

    const ushort* Kf_bh = Kf + (size_t)bh * SS * QKH_D;
    const ushort* VT_bh = VT + (size_t)bh * VD_D * SS;
    const int* mrow = mask + b * SS;

    // Q A-frags: rows s0+16w..+15, 6 k-chunks of 32 over the 192 dims
    bf16x8 qf[6];
    {
        const ushort* qbase = qbuf + ((size_t)(b * SS) + s0 + 16 * w + l15) * 3072 + h * QKH_D + q * 8;
#pragma unroll
        for (int k = 0; k < 6; k++) qf[k] = *(const bf16x8*)(qbase + k * 32);
    }

    f32x4 Oacc[2][4];
#pragma unroll
    for (int mt = 0; mt < 2; mt++)
#pragma unroll
        for (int nt = 0; nt < 4; nt++) Oacc[mt][nt] = (f32x4){0.f, 0.f, 0.f, 0.f};
    float m_i[4] = {-3e38f, -3e38f, -3e38f, -3e38f};
    float l_i[4] = {0.f, 0.f, 0.f, 0.f};

    for (int st = t0s; st < t1s; st++) {
        const int t0 = st * 64;
        // ---- stage K-tile (64 rows x 24 chunks), coalesced + swizzled ----
#pragma unroll
        for (int i = 0; i < 6; i++) {
            int g = 6 * w + i;                 // 0..23
            int rg = g & 7, cg = g >> 3;       // row-group, chunk-group
            int row = rg * 8 + r7;
            int ch = cg * 8 + (c7 ^ r7);
            gload_lds16(Kf_bh + (size_t)(t0 + row) * QKH_D + ch * 8,
                        Kt + g * 512 + lane * 8);
        }
        __syncthreads();
        // ---- scores S(16 x 64) for my m-tile ----
        f32x4 sa[4];
#pragma unroll
        for (int c = 0; c < 4; c++) sa[c] = (f32x4){0.f, 0.f, 0.f, 0.f};
#pragma unroll
        for (int k = 0; k < 6; k++) {
#pragma unroll
            for (int c = 0; c < 4; c++) {
                bf16x8 kb = *(const bf16x8*)(Kt + ktidx(16 * c + l15, 4 * k + q));
                sa[c] = __builtin_amdgcn_mfma_f32_16x16x32_bf16(qf[k], kb, sa[c], 0, 0, 0);
            }
        }
        // ---- online softmax over 64 cols ----
        int mv[4];
#pragma unroll
        for (int c = 0; c < 4; c++) mv[c] = mrow[t0 + 16 * c + l15];
        float alpha[4];
#pragma unroll
        for (int r = 0; r < 4; r++) {
            const int srow = s0 + 16 * w + 4 * q + r;
            float s_c[4];
#pragma unroll
            for (int c = 0; c < 4; c++) {
                s_c[c] = sa[c][r] * SCL;
                int col = t0 + 16 * c + l15;
                if (col > srow || mv[c] == 0) s_c[c] = -1e30f;
            }
            float mx = fmaxf(fmaxf(s_c[0], s_c[1]), fmaxf(s_c[2], s_c[3]));
            mx = fmaxf(mx, __shfl_xor(mx, 1)); mx = fmaxf(mx, __shfl_xor(mx, 2));
            mx = fmaxf(mx, __shfl_xor(mx, 4)); mx = fmaxf(mx, __shfl_xor(mx, 8));
            float mn = fmaxf(m_i[r], mx);
            alpha[r] = exp2f(m_i[r] - mn);
            m_i[r] = mn;
            float ps = 0.f;
            const int prow = 16 * w + 4 * q + r;
#pragma unroll
            for (int c = 0; c < 4; c++) {
                float pc = (s_c[c] <= -1e29f) ? 0.f : exp2f(s_c[c] - mn);
                ps += pc;
                Pt[prow * PTL + 16 * c + l15] = f2bf(pc);
            }
            ps += __shfl_xor(ps, 1); ps += __shfl_xor(ps, 2);
            ps += __shfl_xor(ps, 4); ps += __shfl_xor(ps, 8);
            l_i[r] = l_i[r] * alpha[r] + ps;
        }
        if (l15 == 0) {
#pragma unroll
            for (int r = 0; r < 4; r++) alpha_sh[16 * w + 4 * q + r] = alpha[r];
        }
        __syncthreads();
        // ---- PV: O^T d-slice [32w,+32) over 64 s, 64 t ----
        float av[4];
#pragma unroll
        for (int nt = 0; nt < 4; nt++) av[nt] = alpha_sh[16 * nt + l15];
#pragma unroll
        for (int mt = 0; mt < 2; mt++)
#pragma unroll
            for (int nt = 0; nt < 4; nt++) {
                Oacc[mt][nt][0] *= av[nt]; Oacc[mt][nt][1] *= av[nt];
                Oacc[mt][nt][2] *= av[nt]; Oacc[mt][nt][3] *= av[nt];
            }
        bf16x8 pb[4][2];
#pragma unroll
        for (int nt = 0; nt < 4; nt++)
#pragma unroll
            for (int kt = 0; kt < 2; kt++)
                pb[nt][kt] = *(const bf16x8*)(Pt + (16 * nt + l15) * PTL + kt * 32 + q * 8);
#pragma unroll
        for (int mt = 0; mt < 2; mt++) {
#pragma unroll
            for (int kt = 0; kt < 2; kt++) {
                bf16x8 af = *(const bf16x8*)(VT_bh + (size_t)(32 * w + 16 * mt + l15) * SS + t0 + kt * 32 + q * 8);
#pragma unroll
                for (int nt = 0; nt < 4; nt++)
                    Oacc[mt][nt] = __builtin_amdgcn_mfma_f32_16x16x32_bf16(af, pb[nt][kt], Oacc[mt][nt], 0, 0, 0);
            }
        }
        __syncthreads();
    }

    // ---- epilogue ----
    if (l15 == 0) {
#pragma unroll
        for (int r = 0; r < 4; r++)
            linv_sh[16 * w + 4 * q + r] = (l_i[r] > 0.f) ? 1.f / l_i[r] : 0.f;
    }
    __syncthreads();

    if (!partial) {
#pragma unroll
        for (int mt = 0; mt < 2; mt++)
#pragma unroll
            for (int nt = 0; nt < 4; nt++) {
                float lv = linv_sh[16 * nt + l15];
                int s = s0 + 16 * nt + l15;
                int d = 32 * w + 16 * mt + 4 * q;
                ushort4 pk;
                pk.x = f2bf(Oacc[mt][nt][0] * lv); pk.y = f2bf(Oacc[mt][nt][1] * lv);
                pk.z = f2bf(Oacc[mt][nt][2] * lv); pk.w = f2bf(Oacc[mt][nt][3] * lv);
                *(ushort4*)(o_heads + (size_t)(b * SS + s) * 2048 + h * VD_D + d) = pk;
            }
    } else {
        const int sp = (t0s != 0);
        const int p = bh * 26 + (qt - 19) * 2 + sp;
#pragma unroll
        for (int mt = 0; mt < 2; mt++)
#pragma unroll
            for (int nt = 0; nt < 4; nt++) {
                float lv = linv_sh[16 * nt + l15];
                int rl = 16 * nt + l15;
                int d = 32 * w + 16 * mt + 4 * q;
                ushort4 pk;
                pk.x = f2bf(Oacc[mt][nt][0] * lv); pk.y = f2bf(Oacc[mt][nt][1] * lv);
                pk.z = f2bf(Oacc[mt][nt][2] * lv); pk.w = f2bf(Oacc[mt][nt][3] * lv);
                *(ushort4*)(Opart + ((size_t)p * 64 + rl) * 128 + d) = pk;
            }
        if (l15 == 0) {
#pragma unroll
            for (int r = 0; r < 4; r++)
                mlbuf[p * 64 + 16 * w + 4 * q + r] = make_float2(m_i[r], l_i[r]);
        }
    }
}

// ---------------------------------------------------------------------------
// Merge span0/span1 partials for qt>=19.  grid 416 (= 32bh x 13qt) x 256.
// ---------------------------------------------------------------------------
__launch_bounds__(256)
__global__ void attn_merge(const ushort* __restrict__ Opart, const float2* __restrict__ mlbuf,
                           ushort* __restrict__ o_heads)
{
    int bh = blockIdx.x & 31, qi = blockIdx.x >> 5;
    int b = bh >> 4, h = bh & 15;
    int qt = 19 + qi;
    int t = threadIdx.x;
    int row = t >> 2, dbase = (t & 3) * 32;
    int p0 = bh * 26 + qi * 2, p1 = p0 + 1;
    float2 ml0 = mlbuf[p0 * 64 + row], ml1 = mlbuf[p1 * 64 + row];
    float M = fmaxf(ml0.x, ml1.x);
    float w0 = (ml0.y > 0.f) ? exp2f(ml0.x - M) * ml0.y : 0.f;
    float w1 = (ml1.y > 0.f) ? exp2f(ml1.x - M) * ml1.y : 0.f;
    float den = w0 + w1;
    float inv = (den > 0.f) ? 1.f / den : 0.f;
    w0 *= inv; w1 *= inv;
    int s = qt * 64 + row;
    const ushort* O0 = Opart + ((size_t)p0 * 64 + row) * 128 + dbase;
    const ushort* O1 = Opart + ((size_t)p1 * 64 + row) * 128 + dbase;
    ushort* dst = o_heads + (size_t)(b * SS + s) * 2048 + h * VD_D + dbase;
#pragma unroll
    for (int c = 0; c < 32; c += 8) {
        bf16x8 a = *(const bf16x8*)(O0 + c);
        bf16x8 bb = *(const bf16x8*)(O1 + c);
        bf16x8 o;
#pragma unroll
        for (int j = 0; j < 8; j++)
            o[j] = (short)f2bf(w0 * bf2f((unsigned short)a[j]) + w1 * bf2f((unsigned short)bb[j]));
        *(bf16x8*)(dst + c) = o;
    }
}

extern "C" void kernel_launch(void* const* d_in, const int* in_sizes, int n_in,
                              void* d_out, int out_size, void* d_ws, size_t ws_size,
                              hipStream_t stream)
{
    const float* x        = (const float*)d_in[0];
    const int*   mask     = (const int*)d_in[1];
    const float* wq_a_w   = (const float*)d_in[2];
    const float* wq_a_b   = (const float*)d_in[3];
    const float* q_norm_w = (const float*)d_in[4];
    const float* wq_b_w   = (const float*)d_in[5];
    const float* wq_b_b   = (const float*)d_in[6];
    const float* wkv_a_w  = (const float*)d_in[7];
    const float* wkv_a_b  = (const float*)d_in[8];
    const float* kv_norm_w= (const float*)d_in[9];
    const float* wkv_b_w  = (const float*)d_in[10];
    const float* wo_w     = (const float*)d_in[11];
    const float* wo_b     = (const float*)d_in[12];
    float* out = (float*)d_out;

    // Workspace layout (108,527,616 B):
    //  A [0,25165824):          wq_a_bf (ph0-1) -> qbuf bf16 (ph3-10)
    //  B [25165824,50331648):   q_a f32 (ph1-2) -> Kf bf16 (ph7-10)
    //  C [50331648,67108864):   x_bf (ph0-4)    -> VT bf16 (ph9-10)
    //  D [67108864,83886080):   q_a_bf (ph2-3) / kvf f32 (ph4-5) / o_heads (ph10-11)
    //  E+F [83886080,97517568): wq_b_bf,kvbf,wkv_b_bf (ph0-9) -> Opart (ph10)
    //  G [97517568,105906176):  wo_bf (ph0-11)
    //  H [105906176,108527616): wkv_a_bf (ph0-4) -> mlbuf (ph10)
    char* W = (char*)d_ws;
    ushort* wq_a_bf = (ushort*)(W + 0);
    ushort* qbuf    = (ushort*)(W + 0);
    float*  q_a     = (float*)(W + 25165824);
    ushort* Kf      = (ushort*)(W + 25165824);
    ushort* x_bf    = (ushort*)(W + 50331648);
    ushort* VT      = (ushort*)(W + 50331648);
    ushort* q_a_bf  = (ushort*)(W + 67108864);
    float*  kvf     = (float*)(W + 67108864);
    ushort* o_heads = (ushort*)(W + 67108864);
    ushort* wq_b_bf = (ushort*)(W + 83886080);
    ushort* kvbf    = (ushort*)(W + 83886080);
    ushort* Opart   = (ushort*)(W + 83886080);   // 832*64*128*2 = 13,631,488
    ushort* wkv_b_bf= (ushort*)(W + 93323264);
    ushort* wo_bf   = (ushort*)(W + 97517568);
    ushort* wkv_a_bf= (ushort*)(W + 105906176);
    float2* mlbuf   = (float2*)(W + 105906176);  // 832*64*8 = 425,984

    // 0. converts to bf16
    conv_bf<<<2048, 256, 0, stream>>>(x, x_bf, MROWS * HH / 4);
    conv_bf<<<2048, 256, 0, stream>>>(wq_a_w, wq_a_bf, QLL * HH / 4);
    conv_bf<<<2048, 256, 0, stream>>>(wq_b_w, wq_b_bf, 3072 * QLL / 4);
    conv_bf<<<1024, 256, 0, stream>>>(wkv_a_w, wkv_a_bf, 576 * HH / 4);
    conv_bf<<<1024, 256, 0, stream>>>(wkv_b_w, wkv_b_bf, NHH * 256 * 512 / 4);
    conv_bf<<<2048, 256, 0, stream>>>(wo_w, wo_bf, HH * 2048 / 4);

    // 1. q_a = x @ wq_a^T + b        (f32 C)
    gemm_bf<float><<<dim3(QLL/128, MROWS/128, 1), 256, 0, stream>>>(
        x_bf, HH, 0, 0, wq_a_bf, HH, 0, 0, wq_a_b, q_a, QLL, 0, 0, MROWS, QLL, HH);
    // 2. rms_norm -> q_a_bf
    rmsnorm_bf<<<MROWS, 256, 0, stream>>>(q_a, q_norm_w, q_a_bf, QLL);
    // 3. q = q_a_bf @ wq_b^T + b -> qbuf bf16
    gemm_bf<ushort><<<dim3(3072/128, MROWS/128, 1), 256, 0, stream>>>(
        q_a_bf, QLL, 0, 0, wq_b_bf, QLL, 0, 0, wq_b_b, qbuf, 3072, 0, 0, MROWS, 3072, QLL);
    // 4. kv_full = x @ wkv_a^T + b   (f32 C, N=576 guarded)
    gemm_bf<float><<<dim3(5, MROWS/128, 1), 256, 0, stream>>>(
        x_bf, HH, 0, 0, wkv_a_bf, HH, 0, 0, wkv_a_b, kvf, 576, 0, 0, MROWS, 576, HH);
    // 5. finalize kv (rms + rope) -> kvbf
    finalize_kv<<<MROWS, 256, 0, stream>>>(kvf, kv_norm_w, kvbf);
    // 6. rope q_pe in place on qbuf
    rope_q_kernel<<<dim3(MROWS, 4), 256, 0, stream>>>(qbuf);
    // 7. Kf[b,h] = kv_lat @ W_UK[h]^T   (M=2048,N=128,K=512, z=32)
    gemm_bf<ushort><<<dim3(1, SS/128, 32), 256, 0, stream>>>(
        kvbf, 576, (size_t)SS * 576, 0,
        wkv_b_bf, 512, 0, (size_t)256 * 512,
        nullptr, Kf, QKH_D, (size_t)NHH * SS * QKH_D, (size_t)SS * QKH_D,
        SS, NOPE_D, 512);
    // 8. k_pe broadcast into Kf cols 128..191
    copy_kpe<<<MROWS, 256, 0, stream>>>(kvbf, Kf);
    // 9. VT[b,h] = W_UV[h] @ kv_lat^T   (M=128,N=2048,K=512, z=32)
    gemm_bf<ushort><<<dim3(SS/128, 1, 32), 256, 0, stream>>>(
        wkv_b_bf + (size_t)128 * 512, 512, 0, (size_t)256 * 512,
        kvbf, 576, (size_t)SS * 576, 0,
        nullptr, VT, SS, (size_t)NHH * VD_D * SS, (size_t)VD_D * SS,
        VD_D, SS, 512);
    // 10. split-K MFMA flash attention (1440 blocks, big-first) + merge
    attn_mfma<<<NJOB * 32, 256, 0, stream>>>(qbuf, Kf, VT, mask, o_heads, Opart, mlbuf);
    attn_merge<<<13 * 32, 256, 0, stream>>>(Opart, mlbuf, o_heads);
    // 11. out = o_heads @ wo^T + b
    gemm_bf<float><<<dim3(HH/128, MROWS/128, 1), 256, 0, stream>>>(
        o_heads, NHH * VD_D, 0, 0, wo_bf, NHH * VD_D, 0, 0, wo_b, out, HH, 0, 0,
        MROWS, HH, NHH * VD_D);
}